// Round 4
// baseline (375.921 us; speedup 1.0000x reference)
//
#include <hip/hip_runtime.h>
#include <hip/hip_bf16.h>

typedef __bf16 bf16x8 __attribute__((ext_vector_type(8)));
typedef __bf16 bf16x4 __attribute__((ext_vector_type(4)));
typedef float  f32x4  __attribute__((ext_vector_type(4)));

#define MFMA16(A, B, C) __builtin_amdgcn_mfma_f32_16x16x32_bf16((A), (B), (C), 0, 0, 0)

// problem sizes (fixed)
static constexpr int TB = 4;        // batch
static constexpr int TT = 2048;     // seq len
static constexpr int TC = 1024;     // embd
static constexpr int TH = 16;       // heads
static constexpr int TD = 64;       // head dim
static constexpr int TM = TB * TT;  // 8192 token rows

// async global->LDS, 16B per lane; LDS dest must be wave-uniform base (lane*16 implied)
__device__ __forceinline__ void gload16(const __bf16* g, __bf16* l) {
  __builtin_amdgcn_global_load_lds(
      (const __attribute__((address_space(1))) unsigned int*)g,
      (__attribute__((address_space(3))) unsigned int*)l, 16, 0, 0);
}

// ---------------------------------------------------------------------------
// f32 -> bf16 elementwise convert (vectorized), n4 = n/4
__global__ __launch_bounds__(256) void k_convert(const float* __restrict__ in,
                                                 __bf16* __restrict__ out, int n4) {
  int stride = gridDim.x * blockDim.x;
  for (int i = blockIdx.x * blockDim.x + threadIdx.x; i < n4; i += stride) {
    float4 v = *(const float4*)(in + (size_t)i * 4);
    bf16x4 o;
    o[0] = (__bf16)v.x; o[1] = (__bf16)v.y; o[2] = (__bf16)v.z; o[3] = (__bf16)v.w;
    *(bf16x4*)(out + (size_t)i * 4) = o;
  }
}

// ---------------------------------------------------------------------------
// W [K][N] f32 row-major  ->  Wt [N][K] bf16 row-major (transpose + convert)
__global__ __launch_bounds__(256) void k_transpose_w(const float* __restrict__ w,
                                                     __bf16* __restrict__ wt,
                                                     int K, int N) {
  __shared__ __align__(16) __bf16 tile[64][72];  // [k][n], +8 pad
  const int k0 = blockIdx.y * 64, n0 = blockIdx.x * 64;
  const int tid = threadIdx.x;
#pragma unroll
  for (int it = 0; it < 4; ++it) {
    int c = tid + it * 256;
    int row = c >> 4, cc = (c & 15) * 4;
    float4 v = *(const float4*)(w + (size_t)(k0 + row) * N + n0 + cc);
    tile[row][cc + 0] = (__bf16)v.x;
    tile[row][cc + 1] = (__bf16)v.y;
    tile[row][cc + 2] = (__bf16)v.z;
    tile[row][cc + 3] = (__bf16)v.w;
  }
  __syncthreads();
#pragma unroll
  for (int it = 0; it < 2; ++it) {
    int c = tid + it * 256;
    int n = c >> 3, kk = (c & 7) * 8;
    bf16x8 v;
#pragma unroll
    for (int j = 0; j < 8; ++j) v[j] = tile[kk + j][n];
    *(bf16x8*)(wt + (size_t)(n0 + n) * K + k0 + kk) = v;
  }
}

// ---------------------------------------------------------------------------
// V [bh][t][d] -> Vt [bh][d][t]
__global__ __launch_bounds__(256) void k_transpose_v(const __bf16* __restrict__ V,
                                                     __bf16* __restrict__ Vt) {
  __shared__ __align__(16) __bf16 tile[64][72];  // [t][d]
  const int bh = blockIdx.y, t0 = blockIdx.x * 64;
  const int tid = threadIdx.x;
#pragma unroll
  for (int it = 0; it < 2; ++it) {
    int c = tid + it * 256;
    int row = c >> 3, cc = (c & 7) * 8;
    *(bf16x8*)&tile[row][cc] =
        *(const bf16x8*)(V + ((size_t)bh * TT + t0 + row) * TD + cc);
  }
  __syncthreads();
#pragma unroll
  for (int it = 0; it < 2; ++it) {
    int c = tid + it * 256;
    int d = c >> 3, tt = (c & 7) * 8;
    bf16x8 v;
#pragma unroll
    for (int j = 0; j < 8; ++j) v[j] = tile[tt + j][d];
    *(bf16x8*)(Vt + ((size_t)bh * TD + d) * TT + t0 + tt) = v;
  }
}

// ---------------------------------------------------------------------------
// C[M][N] = A[M][1024] @ Bt[N][1024]^T, bf16 in / f32 acc. m97 structure:
// linear LDS [128][32] + global_load_lds width 16, 2 barriers / K-step,
// bijective XCD swizzle on the flat workgroup id (T1).
// EPI==0: store f32 to outf[M][N].  EPI==1: scatter qkv (q scaled 1/8) bf16.
template <int EPI>
__global__ __launch_bounds__(256, 2) void k_gemm(const __bf16* __restrict__ A,
                                                 const __bf16* __restrict__ Bt,
                                                 int N, float* __restrict__ outf,
                                                 __bf16* __restrict__ Qo,
                                                 __bf16* __restrict__ Ko,
                                                 __bf16* __restrict__ Vo) {
  __shared__ __align__(16) __bf16 As[128][32];
  __shared__ __align__(16) __bf16 Bs[128][32];
  // XCD-aware swizzle (nwg % 8 == 0 for both launches)
  const int gx = gridDim.x;
  const int nwg = gx * gridDim.y;
  int id = blockIdx.y * gx + blockIdx.x;
  id = (id & 7) * (nwg >> 3) + (id >> 3);
  const int bm = id / gx, bn = id % gx;
  const int tid = threadIdx.x, lane = tid & 63, wid = tid >> 6;
  const int wr = wid >> 1, wc = wid & 1;
  const int lr = lane & 15, lg = lane >> 4, lg8 = lg << 3;

  f32x4 acc[4][4];
  const f32x4 zero = {0.f, 0.f, 0.f, 0.f};
#pragma unroll
  for (int mi = 0; mi < 4; ++mi)
#pragma unroll
    for (int ni = 0; ni < 4; ++ni) acc[mi][ni] = zero;

  const __bf16* Ab = A + (size_t)bm * 128 * 1024;
  const __bf16* Bb = Bt + (size_t)bn * 128 * 1024;

  // staging: wave w covers rows [w*32, w*32+32), two 1KB wave-loads each for A,B
  const int srow = wid * 32 + (lane >> 2);  // +16 for second load
  const int scol = (lane & 3) * 8;
  __bf16* ldsA = &As[0][0] + wid * 1024;    // elements; +512 for second load
  __bf16* ldsB = &Bs[0][0] + wid * 1024;

  for (int k0 = 0; k0 < 1024; k0 += 32) {
    gload16(Ab + (size_t)srow * 1024 + k0 + scol, ldsA);
    gload16(Ab + (size_t)(srow + 16) * 1024 + k0 + scol, ldsA + 512);
    gload16(Bb + (size_t)srow * 1024 + k0 + scol, ldsB);
    gload16(Bb + (size_t)(srow + 16) * 1024 + k0 + scol, ldsB + 512);
    __syncthreads();  // vmcnt(0) drain inserted by compiler

    bf16x8 af[4], bfr[4];
#pragma unroll
    for (int mi = 0; mi < 4; ++mi)
      af[mi] = *(const bf16x8*)&As[wr * 64 + mi * 16 + lr][lg8];
#pragma unroll
    for (int ni = 0; ni < 4; ++ni)
      bfr[ni] = *(const bf16x8*)&Bs[wc * 64 + ni * 16 + lr][lg8];
#pragma unroll
    for (int mi = 0; mi < 4; ++mi)
#pragma unroll
      for (int ni = 0; ni < 4; ++ni)
        acc[mi][ni] = MFMA16(af[mi], bfr[ni], acc[mi][ni]);
    __syncthreads();  // protect LDS from next iteration's staging
  }

  // epilogue. C layout: row = (lane>>4)*4 + j, col = lane&15 (m89-verified)
  const int rb = bm * 128 + wr * 64 + lg * 4;
  const int cb = bn * 128 + wc * 64 + lr;
#pragma unroll
  for (int mi = 0; mi < 4; ++mi) {
#pragma unroll
    for (int ni = 0; ni < 4; ++ni) {
#pragma unroll
      for (int j = 0; j < 4; ++j) {
        float v = acc[mi][ni][j];
        int r = rb + mi * 16 + j;
        int c = cb + ni * 16;
        if constexpr (EPI == 0) {
          outf[(size_t)r * N + c] = v;
        } else {
          int which = c >> 10, within = c & 1023;
          int h = within >> 6, d = within & 63;
          int b = r >> 11, t = r & 2047;
          size_t idx = (((size_t)(b * TH + h)) * TT + t) * TD + d;
          if (which == 0)
            Qo[idx] = (__bf16)(v * 0.125f);  // fold 1/sqrt(64), exact in bf16
          else if (which == 1)
            Ko[idx] = (__bf16)v;
          else
            Vo[idx] = (__bf16)v;
        }
      }
    }
  }
}

// ---------------------------------------------------------------------------
// causal flash attention v4: swapped QK^T + static-max softmax (order-free,
// additive partials) + PARTNER-WAVE KEY SPLIT: each 32-row chunk's key tiles
// are split even/odd across 2 partner waves; partial (O,l) merged via one LDS
// add. 4096 waves -> 16 waves/CU (was 8) at unchanged L2 traffic.
// Q [bh][t][d] (pre-scaled 1/8), K [bh][t][d], Vt [bh][d][t]; Y bf16 [b*T+t][C]
__global__ __launch_bounds__(256, 4) void k_attn(const __bf16* __restrict__ Qg,
                                                 const __bf16* __restrict__ Kg,
                                                 const __bf16* __restrict__ Vt,
                                                 __bf16* __restrict__ Y) {
  __shared__ __align__(16) __bf16 Plds[4][2][16][72];  // per-wave [f][q][key]
  __shared__ __align__(16) float mbuf[2][64][40];      // per-pair merge buffer
  const int bh = blockIdx.y, x = blockIdx.x;  // x in [0,16)
  const int tid = threadIdx.x, lane = tid & 63, w = tid >> 6;
  const int lr = lane & 15, lg = lane >> 4, lg8 = lg << 3, lg4 = lg << 2;
  const int a = w >> 1;      // local pair slot (0,1)
  const int s = w & 1;       // partner parity: s processes tiles kt ≡ s (mod 2)
  const int p = x * 2 + a;   // chunk-pair id 0..31

  const __bf16* Qb = Qg + ((size_t)bh * TT) * TD;
  const __bf16* Kb = Kg + ((size_t)bh * TT) * TD;
  const __bf16* Vb = Vt + ((size_t)bh * TD) * TT;
  const int b = bh >> 4, hh = bh & 15;
  __bf16* Yb = Y + ((size_t)b * TT) * TC + hh * TD;

  constexpr float LOG2E = 1.44269504f;
  constexpr float CM = 12.0f * LOG2E;  // static max m0 = 12

  const f32x4 zero = {0.f, 0.f, 0.f, 0.f};

#pragma unroll 1
  for (int half = 0; half < 2; ++half) {
    const int chunk = half ? (63 - p) : p;  // 32 q-rows; pair totals 33 tiles
    const int qw = chunk << 5;
    const int nkt = (chunk >> 1) + 1;

    // Q as B-frag: col(q)=lr, k(d)=lg*8+j (+32 for h=1)
    bf16x8 qf[2][2];
#pragma unroll
    for (int f = 0; f < 2; ++f)
#pragma unroll
      for (int h = 0; h < 2; ++h)
        qf[f][h] = *(const bf16x8*)(Qb + (size_t)(qw + f * 16 + lr) * TD + h * 32 + lg8);

    f32x4 o[2][4];
    f32x4 l4[2];
#pragma unroll
    for (int f = 0; f < 2; ++f) {
      l4[f] = zero;
#pragma unroll
      for (int df = 0; df < 4; ++df) o[f][df] = zero;
    }

    for (int kt = s; kt < nkt; kt += 2) {
      const int kb = kt << 6;
      // K as A-frag: row(key)=lr, k(d)=lg*8+j
      bf16x8 kA[4][2];
#pragma unroll
      for (int kf = 0; kf < 4; ++kf)
#pragma unroll
        for (int h = 0; h < 2; ++h)
          kA[kf][h] = *(const bf16x8*)(Kb + (size_t)(kb + kf * 16 + lr) * TD + h * 32 + lg8);
      // V as B-frag: col(d)=lr, k(key)=lg*8+j; issued early, used by PV
      bf16x8 vB[4][2];
#pragma unroll
      for (int df = 0; df < 4; ++df)
#pragma unroll
        for (int h = 0; h < 2; ++h)
          vB[df][h] = *(const bf16x8*)(Vb + (size_t)(df * 16 + lr) * TT + kb + h * 32 + lg8);

      // S^T = K Q^T: C[row=key=kf*16+lg*4+j][col=q=lr]
      f32x4 s4[2][4];
      __builtin_amdgcn_s_setprio(1);
#pragma unroll
      for (int f = 0; f < 2; ++f)
#pragma unroll
        for (int kf = 0; kf < 4; ++kf) {
          f32x4 z = zero;
          z = MFMA16(kA[kf][0], qf[f][0], z);
          z = MFMA16(kA[kf][1], qf[f][1], z);
          s4[f][kf] = z;
        }
      __builtin_amdgcn_s_setprio(0);

      // static-max exp: p = exp2(s*log2e - CM); mask by arg = -16384
#pragma unroll
      for (int f = 0; f < 2; ++f) {
        const int q = qw + f * 16 + lr;
        const bool diag = (kb + 63 > qw + f * 16);  // wave-uniform per f
#pragma unroll
        for (int kf = 0; kf < 4; ++kf) {
#pragma unroll
          for (int j = 0; j < 4; ++j) {
            float arg = __builtin_fmaf(s4[f][kf][j], LOG2E, -CM);
            if (diag) {
              int key = kb + kf * 16 + lg4 + j;
              if (key > q) arg = -16384.0f;
            }
            s4[f][kf][j] = exp2f(arg);
          }
          l4[f] += s4[f][kf];
          // P write: row=q(lr), cols kf*16+lg*4.. (4 consecutive keys -> b64)
          bf16x4 pk;
#pragma unroll
          for (int j = 0; j < 4; ++j) pk[j] = (__bf16)s4[f][kf][j];
          *(bf16x4*)&Plds[w][f][lr][kf * 16 + lg4] = pk;
        }
      }
      // (compiler inserts lgkmcnt wait for the Plds RAW dependency)

      // PV: P as A-frag (row=q=lr, k=key=lg*8+j +32h), V as B-frag
      __builtin_amdgcn_s_setprio(1);
#pragma unroll
      for (int f = 0; f < 2; ++f) {
        bf16x8 pa0 = *(const bf16x8*)&Plds[w][f][lr][lg8];
        bf16x8 pa1 = *(const bf16x8*)&Plds[w][f][lr][32 + lg8];
#pragma unroll
        for (int df = 0; df < 4; ++df) {
          o[f][df] = MFMA16(pa0, vB[df][0], o[f][df]);
          o[f][df] = MFMA16(pa1, vB[df][1], o[f][df]);
        }
      }
      __builtin_amdgcn_s_setprio(0);
    }

    // merge partner partials (static-max partials are directly additive)
    if (s == 1) {
      float* mb = &mbuf[a][lane][0];
#pragma unroll
      for (int f = 0; f < 2; ++f)
#pragma unroll
        for (int df = 0; df < 4; ++df)
          *(f32x4*)(mb + f * 16 + df * 4) = o[f][df];
      *(f32x4*)(mb + 32) = l4[0];
      *(f32x4*)(mb + 36) = l4[1];
    }
    __syncthreads();
    if (s == 0) {
      const float* mb = &mbuf[a][lane][0];
#pragma unroll
      for (int f = 0; f < 2; ++f)
#pragma unroll
        for (int df = 0; df < 4; ++df)
          o[f][df] += *(const f32x4*)(mb + f * 16 + df * 4);
      l4[0] += *(const f32x4*)(mb + 32);
      l4[1] += *(const f32x4*)(mb + 36);

      // epilogue: reduce l across lg groups (2 shuffles), broadcast, write
#pragma unroll
      for (int f = 0; f < 2; ++f) {
        float L = (l4[f][0] + l4[f][1]) + (l4[f][2] + l4[f][3]);
        L += __shfl_xor(L, 16);
        L += __shfl_xor(L, 32);
        const float inv = 1.0f / L;  // for q = qw + f*16 + lr (uniform over lg)
#pragma unroll
        for (int j = 0; j < 4; ++j) {
          const float invr = __shfl(inv, lg4 + j);  // inv for row lg*4+j
          const int row = qw + f * 16 + lg4 + j;
#pragma unroll
          for (int df = 0; df < 4; ++df)
            Yb[(size_t)row * TC + df * 16 + lr] = (__bf16)(o[f][df][j] * invr);
        }
      }
    }
    __syncthreads();  // mbuf reused by next half
  }
}

// ---------------------------------------------------------------------------
extern "C" void kernel_launch(void* const* d_in, const int* in_sizes, int n_in,
                              void* d_out, int out_size, void* d_ws, size_t ws_size,
                              hipStream_t stream) {
  const float* x  = (const float*)d_in[0];
  const float* Wa = (const float*)d_in[1];
  const float* Wp = (const float*)d_in[2];
  float* out = (float*)d_out;

  char* ws = (char*)d_ws;
  size_t off = 0;
  auto alloc = [&](size_t bytes) { char* p = ws + off; off += bytes; return p; };
  __bf16* xb   = (__bf16*)alloc((size_t)TM * TC * 2);        // 16.8 MB (reused as Y)
  __bf16* wat  = (__bf16*)alloc((size_t)3 * TC * TC * 2);    //  6.3 MB
  __bf16* wpt  = (__bf16*)alloc((size_t)TC * TC * 2);        //  2.1 MB
  __bf16* Qb   = (__bf16*)alloc((size_t)TM * TC * 2);        // 16.8 MB
  __bf16* Kb   = (__bf16*)alloc((size_t)TM * TC * 2);        // 16.8 MB
  __bf16* Vb   = (__bf16*)alloc((size_t)TM * TC * 2);        // 16.8 MB
  __bf16* Vtb  = (__bf16*)alloc((size_t)TM * TC * 2);        // 16.8 MB
  __bf16* Yb   = xb;  // x_bf16 dead after GEMM1; alias as attention output

  // 1. x -> bf16
  k_convert<<<2048, 256, 0, stream>>>(x, xb, (TM * TC) / 4);
  // 2/3. W transposes -> [N][K] bf16
  k_transpose_w<<<dim3(48, 16), 256, 0, stream>>>(Wa, wat, 1024, 3072);
  k_transpose_w<<<dim3(16, 16), 256, 0, stream>>>(Wp, wpt, 1024, 1024);
  // 4. qkv = x @ W_attn, scatter to Q/K/V [B][H][T][D]
  k_gemm<1><<<dim3(24, 64), 256, 0, stream>>>(xb, wat, 3072, nullptr, Qb, Kb, Vb);
  // 5. V -> Vt [B][H][D][T]
  k_transpose_v<<<dim3(32, 64), 256, 0, stream>>>(Vb, Vtb);
  // 6. causal flash attention -> Y bf16 [B*T][C]
  k_attn<<<dim3(16, 64), 256, 0, stream>>>(Qb, Kb, Vtb, Yb);
  // 7. out = Y @ W_proj (f32 out)
  k_gemm<0><<<dim3(8, 64), 256, 0, stream>>>(Yb, wpt, 1024, out, nullptr, nullptr, nullptr);
}

// Round 5
// 241.897 us; speedup vs baseline: 1.5541x; 1.5541x over previous
//
#include <hip/hip_runtime.h>
#include <hip/hip_bf16.h>

typedef __bf16 bf16x8 __attribute__((ext_vector_type(8)));
typedef __bf16 bf16x4 __attribute__((ext_vector_type(4)));
typedef float  f32x4  __attribute__((ext_vector_type(4)));

#define MFMA16(A, B, C) __builtin_amdgcn_mfma_f32_16x16x32_bf16((A), (B), (C), 0, 0, 0)

// problem sizes (fixed)
static constexpr int TB = 4;        // batch
static constexpr int TT = 2048;     // seq len
static constexpr int TC = 1024;     // embd
static constexpr int TH = 16;       // heads
static constexpr int TD = 64;       // head dim
static constexpr int TM = TB * TT;  // 8192 token rows

// async global->LDS, 16B per lane; LDS dest must be wave-uniform base (lane*16 implied)
__device__ __forceinline__ void gload16(const __bf16* g, __bf16* l) {
  __builtin_amdgcn_global_load_lds(
      (const __attribute__((address_space(1))) unsigned int*)g,
      (__attribute__((address_space(3))) unsigned int*)l, 16, 0, 0);
}

// ---------------------------------------------------------------------------
// f32 -> bf16 elementwise convert (vectorized), n4 = n/4
__global__ __launch_bounds__(256) void k_convert(const float* __restrict__ in,
                                                 __bf16* __restrict__ out, int n4) {
  int stride = gridDim.x * blockDim.x;
  for (int i = blockIdx.x * blockDim.x + threadIdx.x; i < n4; i += stride) {
    float4 v = *(const float4*)(in + (size_t)i * 4);
    bf16x4 o;
    o[0] = (__bf16)v.x; o[1] = (__bf16)v.y; o[2] = (__bf16)v.z; o[3] = (__bf16)v.w;
    *(bf16x4*)(out + (size_t)i * 4) = o;
  }
}

// ---------------------------------------------------------------------------
// W [K][N] f32 row-major  ->  Wt [N][K] bf16 row-major (transpose + convert)
__global__ __launch_bounds__(256) void k_transpose_w(const float* __restrict__ w,
                                                     __bf16* __restrict__ wt,
                                                     int K, int N) {
  __shared__ __align__(16) __bf16 tile[64][72];  // [k][n], +8 pad
  const int k0 = blockIdx.y * 64, n0 = blockIdx.x * 64;
  const int tid = threadIdx.x;
#pragma unroll
  for (int it = 0; it < 4; ++it) {
    int c = tid + it * 256;
    int row = c >> 4, cc = (c & 15) * 4;
    float4 v = *(const float4*)(w + (size_t)(k0 + row) * N + n0 + cc);
    tile[row][cc + 0] = (__bf16)v.x;
    tile[row][cc + 1] = (__bf16)v.y;
    tile[row][cc + 2] = (__bf16)v.z;
    tile[row][cc + 3] = (__bf16)v.w;
  }
  __syncthreads();
#pragma unroll
  for (int it = 0; it < 2; ++it) {
    int c = tid + it * 256;
    int n = c >> 3, kk = (c & 7) * 8;
    bf16x8 v;
#pragma unroll
    for (int j = 0; j < 8; ++j) v[j] = tile[kk + j][n];
    *(bf16x8*)(wt + (size_t)(n0 + n) * K + k0 + kk) = v;
  }
}

// ---------------------------------------------------------------------------
// V [bh][t][d] -> Vt [bh][d][t]
__global__ __launch_bounds__(256) void k_transpose_v(const __bf16* __restrict__ V,
                                                     __bf16* __restrict__ Vt) {
  __shared__ __align__(16) __bf16 tile[64][72];  // [t][d]
  const int bh = blockIdx.y, t0 = blockIdx.x * 64;
  const int tid = threadIdx.x;
#pragma unroll
  for (int it = 0; it < 2; ++it) {
    int c = tid + it * 256;
    int row = c >> 3, cc = (c & 7) << 3;
    *(bf16x8*)&tile[row][cc] =
        *(const bf16x8*)(V + ((size_t)bh * TT + t0 + row) * TD + cc);
  }
  __syncthreads();
#pragma unroll
  for (int it = 0; it < 2; ++it) {
    int c = tid + it * 256;
    int d = c >> 3, tt = (c & 7) << 3;
    bf16x8 v;
#pragma unroll
    for (int j = 0; j < 8; ++j) v[j] = tile[tt + j][d];
    *(bf16x8*)(Vt + ((size_t)bh * TD + d) * TT + t0 + tt) = v;
  }
}

// ---------------------------------------------------------------------------
// C[M][N] = A[M][1024] @ Bt[N][1024]^T, bf16 in / f32 acc. m97 structure:
// linear LDS [128][32] + global_load_lds width 16, 2 barriers / K-step,
// bijective XCD swizzle on the flat workgroup id (T1).
// EPI==0: store f32 to outf[M][N].  EPI==1: scatter qkv (q scaled 1/8) bf16.
template <int EPI>
__global__ __launch_bounds__(256, 2) void k_gemm(const __bf16* __restrict__ A,
                                                 const __bf16* __restrict__ Bt,
                                                 int N, float* __restrict__ outf,
                                                 __bf16* __restrict__ Qo,
                                                 __bf16* __restrict__ Ko,
                                                 __bf16* __restrict__ Vo) {
  __shared__ __align__(16) __bf16 As[128][32];
  __shared__ __align__(16) __bf16 Bs[128][32];
  // XCD-aware swizzle (nwg % 8 == 0 for both launches)
  const int gx = gridDim.x;
  const int nwg = gx * gridDim.y;
  int id = blockIdx.y * gx + blockIdx.x;
  id = (id & 7) * (nwg >> 3) + (id >> 3);
  const int bm = id / gx, bn = id % gx;
  const int tid = threadIdx.x, lane = tid & 63, wid = tid >> 6;
  const int wr = wid >> 1, wc = wid & 1;
  const int lr = lane & 15, lg = lane >> 4, lg8 = lg << 3;

  f32x4 acc[4][4];
  const f32x4 zero = {0.f, 0.f, 0.f, 0.f};
#pragma unroll
  for (int mi = 0; mi < 4; ++mi)
#pragma unroll
    for (int ni = 0; ni < 4; ++ni) acc[mi][ni] = zero;

  const __bf16* Ab = A + (size_t)bm * 128 * 1024;
  const __bf16* Bb = Bt + (size_t)bn * 128 * 1024;

  // staging: wave w covers rows [w*32, w*32+32), two 1KB wave-loads each for A,B
  const int srow = wid * 32 + (lane >> 2);  // +16 for second load
  const int scol = (lane & 3) * 8;
  __bf16* ldsA = &As[0][0] + wid * 1024;    // elements; +512 for second load
  __bf16* ldsB = &Bs[0][0] + wid * 1024;

  for (int k0 = 0; k0 < 1024; k0 += 32) {
    gload16(Ab + (size_t)srow * 1024 + k0 + scol, ldsA);
    gload16(Ab + (size_t)(srow + 16) * 1024 + k0 + scol, ldsA + 512);
    gload16(Bb + (size_t)srow * 1024 + k0 + scol, ldsB);
    gload16(Bb + (size_t)(srow + 16) * 1024 + k0 + scol, ldsB + 512);
    __syncthreads();  // vmcnt(0) drain inserted by compiler

    bf16x8 af[4], bfr[4];
#pragma unroll
    for (int mi = 0; mi < 4; ++mi)
      af[mi] = *(const bf16x8*)&As[wr * 64 + mi * 16 + lr][lg8];
#pragma unroll
    for (int ni = 0; ni < 4; ++ni)
      bfr[ni] = *(const bf16x8*)&Bs[wc * 64 + ni * 16 + lr][lg8];
#pragma unroll
    for (int mi = 0; mi < 4; ++mi)
#pragma unroll
      for (int ni = 0; ni < 4; ++ni)
        acc[mi][ni] = MFMA16(af[mi], bfr[ni], acc[mi][ni]);
    __syncthreads();  // protect LDS from next iteration's staging
  }

  // epilogue. C layout: row = (lane>>4)*4 + j, col = lane&15 (m89-verified)
  const int rb = bm * 128 + wr * 64 + lg * 4;
  const int cb = bn * 128 + wc * 64 + lr;
#pragma unroll
  for (int mi = 0; mi < 4; ++mi) {
#pragma unroll
    for (int ni = 0; ni < 4; ++ni) {
#pragma unroll
      for (int j = 0; j < 4; ++j) {
        float v = acc[mi][ni][j];
        int r = rb + mi * 16 + j;
        int c = cb + ni * 16;
        if constexpr (EPI == 0) {
          outf[(size_t)r * N + c] = v;
        } else {
          int which = c >> 10, within = c & 1023;
          int h = within >> 6, d = within & 63;
          int b = r >> 11, t = r & 2047;
          size_t idx = (((size_t)(b * TH + h)) * TT + t) * TD + d;
          if (which == 0)
            Qo[idx] = (__bf16)(v * 0.125f);  // fold 1/sqrt(64), exact in bf16
          else if (which == 1)
            Ko[idx] = (__bf16)v;
          else
            Vo[idx] = (__bf16)v;
        }
      }
    }
  }
}

// ---------------------------------------------------------------------------
// causal flash attention v5 = v4 (partner-wave key split, additive static-max
// partials) with the spill fixed: __launch_bounds__(256,3) (v4's (256,4)
// forced 64 VGPRs -> ~1GB scratch traffic) and V-fragment loads moved AFTER
// the S MFMAs (exp phase hides their latency; -32 regs off the peak live set).
// Q [bh][t][d] (pre-scaled 1/8), K [bh][t][d], Vt [bh][d][t]; Y bf16 [b*T+t][C]
__global__ __launch_bounds__(256, 3) void k_attn(const __bf16* __restrict__ Qg,
                                                 const __bf16* __restrict__ Kg,
                                                 const __bf16* __restrict__ Vt,
                                                 __bf16* __restrict__ Y) {
  __shared__ __align__(16) __bf16 Plds[4][2][16][72];  // per-wave [f][q][key]
  __shared__ __align__(16) float mbuf[2][64][40];      // per-pair merge buffer
  const int bh = blockIdx.y, x = blockIdx.x;  // x in [0,16)
  const int tid = threadIdx.x, lane = tid & 63, w = tid >> 6;
  const int lr = lane & 15, lg = lane >> 4, lg8 = lg << 3, lg4 = lg << 2;
  const int a = w >> 1;      // local pair slot (0,1)
  const int s = w & 1;       // partner parity: s processes tiles kt ≡ s (mod 2)
  const int p = x * 2 + a;   // chunk-pair id 0..31

  const __bf16* Qb = Qg + ((size_t)bh * TT) * TD;
  const __bf16* Kb = Kg + ((size_t)bh * TT) * TD;
  const __bf16* Vb = Vt + ((size_t)bh * TD) * TT;
  const int b = bh >> 4, hh = bh & 15;
  __bf16* Yb = Y + ((size_t)b * TT) * TC + hh * TD;

  constexpr float LOG2E = 1.44269504f;
  constexpr float CM = 12.0f * LOG2E;  // static max m0 = 12

  const f32x4 zero = {0.f, 0.f, 0.f, 0.f};

#pragma unroll 1
  for (int half = 0; half < 2; ++half) {
    const int chunk = half ? (63 - p) : p;  // 32 q-rows; pair totals 33 tiles
    const int qw = chunk << 5;
    const int nkt = (chunk >> 1) + 1;

    // Q as B-frag: col(q)=lr, k(d)=lg*8+j (+32 for h=1)
    bf16x8 qf[2][2];
#pragma unroll
    for (int f = 0; f < 2; ++f)
#pragma unroll
      for (int h = 0; h < 2; ++h)
        qf[f][h] = *(const bf16x8*)(Qb + (size_t)(qw + f * 16 + lr) * TD + h * 32 + lg8);

    f32x4 o[2][4];
    f32x4 l4[2];
#pragma unroll
    for (int f = 0; f < 2; ++f) {
      l4[f] = zero;
#pragma unroll
      for (int df = 0; df < 4; ++df) o[f][df] = zero;
    }

    for (int kt = s; kt < nkt; kt += 2) {
      const int kb = kt << 6;
      // K as A-frag: row(key)=lr, k(d)=lg*8+j
      bf16x8 kA[4][2];
#pragma unroll
      for (int kf = 0; kf < 4; ++kf)
#pragma unroll
        for (int h = 0; h < 2; ++h)
          kA[kf][h] = *(const bf16x8*)(Kb + (size_t)(kb + kf * 16 + lr) * TD + h * 32 + lg8);

      // S^T = K Q^T: C[row=key=kf*16+lg*4+j][col=q=lr]
      f32x4 s4[2][4];
      __builtin_amdgcn_s_setprio(1);
#pragma unroll
      for (int f = 0; f < 2; ++f)
#pragma unroll
        for (int kf = 0; kf < 4; ++kf) {
          f32x4 z = zero;
          z = MFMA16(kA[kf][0], qf[f][0], z);
          z = MFMA16(kA[kf][1], qf[f][1], z);
          s4[f][kf] = z;
        }
      __builtin_amdgcn_s_setprio(0);

      // V as B-frag: col(d)=lr, k(key)=lg*8+j — issued here so the exp phase
      // hides their latency and they don't sit live across the S MFMAs
      bf16x8 vB[4][2];
#pragma unroll
      for (int df = 0; df < 4; ++df)
#pragma unroll
        for (int h = 0; h < 2; ++h)
          vB[df][h] = *(const bf16x8*)(Vb + (size_t)(df * 16 + lr) * TT + kb + h * 32 + lg8);

      // static-max exp: p = exp2(s*log2e - CM); mask by arg = -16384
#pragma unroll
      for (int f = 0; f < 2; ++f) {
        const int q = qw + f * 16 + lr;
        const bool diag = (kb + 63 > qw + f * 16);  // wave-uniform per f
#pragma unroll
        for (int kf = 0; kf < 4; ++kf) {
#pragma unroll
          for (int j = 0; j < 4; ++j) {
            float arg = __builtin_fmaf(s4[f][kf][j], LOG2E, -CM);
            if (diag) {
              int key = kb + kf * 16 + lg4 + j;
              if (key > q) arg = -16384.0f;
            }
            s4[f][kf][j] = exp2f(arg);
          }
          l4[f] += s4[f][kf];
          // P write: row=q(lr), cols kf*16+lg*4.. (4 consecutive keys -> b64)
          bf16x4 pk;
#pragma unroll
          for (int j = 0; j < 4; ++j) pk[j] = (__bf16)s4[f][kf][j];
          *(bf16x4*)&Plds[w][f][lr][kf * 16 + lg4] = pk;
        }
      }
      // (compiler inserts lgkmcnt wait for the Plds RAW dependency)

      // PV: P as A-frag (row=q=lr, k=key=lg*8+j +32h), V as B-frag
      __builtin_amdgcn_s_setprio(1);
#pragma unroll
      for (int f = 0; f < 2; ++f) {
        bf16x8 pa0 = *(const bf16x8*)&Plds[w][f][lr][lg8];
        bf16x8 pa1 = *(const bf16x8*)&Plds[w][f][lr][32 + lg8];
#pragma unroll
        for (int df = 0; df < 4; ++df) {
          o[f][df] = MFMA16(pa0, vB[df][0], o[f][df]);
          o[f][df] = MFMA16(pa1, vB[df][1], o[f][df]);
        }
      }
      __builtin_amdgcn_s_setprio(0);
    }

    // merge partner partials (static-max partials are directly additive)
    if (s == 1) {
      float* mb = &mbuf[a][lane][0];
#pragma unroll
      for (int f = 0; f < 2; ++f)
#pragma unroll
        for (int df = 0; df < 4; ++df)
          *(f32x4*)(mb + f * 16 + df * 4) = o[f][df];
      *(f32x4*)(mb + 32) = l4[0];
      *(f32x4*)(mb + 36) = l4[1];
    }
    __syncthreads();
    if (s == 0) {
      const float* mb = &mbuf[a][lane][0];
#pragma unroll
      for (int f = 0; f < 2; ++f)
#pragma unroll
        for (int df = 0; df < 4; ++df)
          o[f][df] += *(const f32x4*)(mb + f * 16 + df * 4);
      l4[0] += *(const f32x4*)(mb + 32);
      l4[1] += *(const f32x4*)(mb + 36);

      // epilogue: reduce l across lg groups (2 shuffles), broadcast, write
#pragma unroll
      for (int f = 0; f < 2; ++f) {
        float L = (l4[f][0] + l4[f][1]) + (l4[f][2] + l4[f][3]);
        L += __shfl_xor(L, 16);
        L += __shfl_xor(L, 32);
        const float inv = 1.0f / L;  // for q = qw + f*16 + lr (uniform over lg)
#pragma unroll
        for (int j = 0; j < 4; ++j) {
          const float invr = __shfl(inv, lg4 + j);  // inv for row lg*4+j
          const int row = qw + f * 16 + lg4 + j;
#pragma unroll
          for (int df = 0; df < 4; ++df)
            Yb[(size_t)row * TC + df * 16 + lr] = (__bf16)(o[f][df][j] * invr);
        }
      }
    }
    __syncthreads();  // mbuf reused by next half
  }
}

// ---------------------------------------------------------------------------
extern "C" void kernel_launch(void* const* d_in, const int* in_sizes, int n_in,
                              void* d_out, int out_size, void* d_ws, size_t ws_size,
                              hipStream_t stream) {
  const float* x  = (const float*)d_in[0];
  const float* Wa = (const float*)d_in[1];
  const float* Wp = (const float*)d_in[2];
  float* out = (float*)d_out;

  char* ws = (char*)d_ws;
  size_t off = 0;
  auto alloc = [&](size_t bytes) { char* p = ws + off; off += bytes; return p; };
  __bf16* xb   = (__bf16*)alloc((size_t)TM * TC * 2);        // 16.8 MB (reused as Y)
  __bf16* wat  = (__bf16*)alloc((size_t)3 * TC * TC * 2);    //  6.3 MB
  __bf16* wpt  = (__bf16*)alloc((size_t)TC * TC * 2);        //  2.1 MB
  __bf16* Qb   = (__bf16*)alloc((size_t)TM * TC * 2);        // 16.8 MB
  __bf16* Kb   = (__bf16*)alloc((size_t)TM * TC * 2);        // 16.8 MB
  __bf16* Vb   = (__bf16*)alloc((size_t)TM * TC * 2);        // 16.8 MB
  __bf16* Vtb  = (__bf16*)alloc((size_t)TM * TC * 2);        // 16.8 MB
  __bf16* Yb   = xb;  // x_bf16 dead after GEMM1; alias as attention output

  // 1. x -> bf16
  k_convert<<<2048, 256, 0, stream>>>(x, xb, (TM * TC) / 4);
  // 2/3. W transposes -> [N][K] bf16
  k_transpose_w<<<dim3(48, 16), 256, 0, stream>>>(Wa, wat, 1024, 3072);
  k_transpose_w<<<dim3(16, 16), 256, 0, stream>>>(Wp, wpt, 1024, 1024);
  // 4. qkv = x @ W_attn, scatter to Q/K/V [B][H][T][D]
  k_gemm<1><<<dim3(24, 64), 256, 0, stream>>>(xb, wat, 3072, nullptr, Qb, Kb, Vb);
  // 5. V -> Vt [B][H][D][T]
  k_transpose_v<<<dim3(32, 64), 256, 0, stream>>>(Vb, Vtb);
  // 6. causal flash attention -> Y bf16 [B*T][C]
  k_attn<<<dim3(16, 64), 256, 0, stream>>>(Qb, Kb, Vtb, Yb);
  // 7. out = Y @ W_proj (f32 out)
  k_gemm<0><<<dim3(8, 64), 256, 0, stream>>>(Yb, wpt, 1024, out, nullptr, nullptr, nullptr);
}

// Round 7
// 195.295 us; speedup vs baseline: 1.9249x; 1.2386x over previous
//
#include <hip/hip_runtime.h>
#include <hip/hip_bf16.h>

typedef __bf16 bf16x8 __attribute__((ext_vector_type(8)));
typedef __bf16 bf16x4 __attribute__((ext_vector_type(4)));
typedef float  f32x4  __attribute__((ext_vector_type(4)));

#define MFMA16(A, B, C) __builtin_amdgcn_mfma_f32_16x16x32_bf16((A), (B), (C), 0, 0, 0)

// problem sizes (fixed)
static constexpr int TB = 4;        // batch
static constexpr int TT = 2048;     // seq len
static constexpr int TC = 1024;     // embd
static constexpr int TH = 16;       // heads
static constexpr int TD = 64;       // head dim
static constexpr int TM = TB * TT;  // 8192 token rows

// async global->LDS, 16B per lane; LDS dest must be wave-uniform base (lane*16 implied)
__device__ __forceinline__ void gload16(const __bf16* g, __bf16* l) {
  __builtin_amdgcn_global_load_lds(
      (const __attribute__((address_space(1))) unsigned int*)g,
      (__attribute__((address_space(3))) unsigned int*)l, 16, 0, 0);
}

// ---------------------------------------------------------------------------
// f32 -> bf16 elementwise convert (vectorized), n4 = n/4
__global__ __launch_bounds__(256) void k_convert(const float* __restrict__ in,
                                                 __bf16* __restrict__ out, int n4) {
  int stride = gridDim.x * blockDim.x;
  for (int i = blockIdx.x * blockDim.x + threadIdx.x; i < n4; i += stride) {
    float4 v = *(const float4*)(in + (size_t)i * 4);
    bf16x4 o;
    o[0] = (__bf16)v.x; o[1] = (__bf16)v.y; o[2] = (__bf16)v.z; o[3] = (__bf16)v.w;
    *(bf16x4*)(out + (size_t)i * 4) = o;
  }
}

// ---------------------------------------------------------------------------
// W [K][N] f32 row-major  ->  Wt [N][K] bf16 row-major (transpose + convert)
__global__ __launch_bounds__(256) void k_transpose_w(const float* __restrict__ w,
                                                     __bf16* __restrict__ wt,
                                                     int K, int N) {
  __shared__ __align__(16) __bf16 tile[64][72];  // [k][n], +8 pad
  const int k0 = blockIdx.y * 64, n0 = blockIdx.x * 64;
  const int tid = threadIdx.x;
#pragma unroll
  for (int it = 0; it < 4; ++it) {
    int c = tid + it * 256;
    int row = c >> 4, cc = (c & 15) * 4;
    float4 v = *(const float4*)(w + (size_t)(k0 + row) * N + n0 + cc);
    tile[row][cc + 0] = (__bf16)v.x;
    tile[row][cc + 1] = (__bf16)v.y;
    tile[row][cc + 2] = (__bf16)v.z;
    tile[row][cc + 3] = (__bf16)v.w;
  }
  __syncthreads();
#pragma unroll
  for (int it = 0; it < 2; ++it) {
    int c = tid + it * 256;
    int n = c >> 3, kk = (c & 7) * 8;
    bf16x8 v;
#pragma unroll
    for (int j = 0; j < 8; ++j) v[j] = tile[kk + j][n];
    *(bf16x8*)(wt + (size_t)(n0 + n) * K + k0 + kk) = v;
  }
}

// ---------------------------------------------------------------------------
// V [bh][t][d] -> Vt [bh][d][t]
__global__ __launch_bounds__(256) void k_transpose_v(const __bf16* __restrict__ V,
                                                     __bf16* __restrict__ Vt) {
  __shared__ __align__(16) __bf16 tile[64][72];  // [t][d]
  const int bh = blockIdx.y, t0 = blockIdx.x * 64;
  const int tid = threadIdx.x;
#pragma unroll
  for (int it = 0; it < 2; ++it) {
    int c = tid + it * 256;
    int row = c >> 3, cc = (c & 7) << 3;
    *(bf16x8*)&tile[row][cc] =
        *(const bf16x8*)(V + ((size_t)bh * TT + t0 + row) * TD + cc);
  }
  __syncthreads();
#pragma unroll
  for (int it = 0; it < 2; ++it) {
    int c = tid + it * 256;
    int d = c >> 3, tt = (c & 7) << 3;
    bf16x8 v;
#pragma unroll
    for (int j = 0; j < 8; ++j) v[j] = tile[tt + j][d];
    *(bf16x8*)(Vt + ((size_t)bh * TD + d) * TT + t0 + tt) = v;
  }
}

// ---------------------------------------------------------------------------
// C[M][N] = A[M][1024] @ Bt[N][1024]^T, bf16 in / f32 acc. m97 structure:
// linear LDS [128][32] + global_load_lds width 16, 2 barriers / K-step,
// bijective XCD swizzle on the flat workgroup id (T1).
// EPI==0: store f32 to outf[M][N].  EPI==1: scatter qkv (q scaled 1/8) bf16.
template <int EPI>
__global__ __launch_bounds__(256, 2) void k_gemm(const __bf16* __restrict__ A,
                                                 const __bf16* __restrict__ Bt,
                                                 int N, float* __restrict__ outf,
                                                 __bf16* __restrict__ Qo,
                                                 __bf16* __restrict__ Ko,
                                                 __bf16* __restrict__ Vo) {
  __shared__ __align__(16) __bf16 As[128][32];
  __shared__ __align__(16) __bf16 Bs[128][32];
  // XCD-aware swizzle (nwg % 8 == 0 for both launches)
  const int gx = gridDim.x;
  const int nwg = gx * gridDim.y;
  int id = blockIdx.y * gx + blockIdx.x;
  id = (id & 7) * (nwg >> 3) + (id >> 3);
  const int bm = id / gx, bn = id % gx;
  const int tid = threadIdx.x, lane = tid & 63, wid = tid >> 6;
  const int wr = wid >> 1, wc = wid & 1;
  const int lr = lane & 15, lg = lane >> 4, lg8 = lg << 3;

  f32x4 acc[4][4];
  const f32x4 zero = {0.f, 0.f, 0.f, 0.f};
#pragma unroll
  for (int mi = 0; mi < 4; ++mi)
#pragma unroll
    for (int ni = 0; ni < 4; ++ni) acc[mi][ni] = zero;

  const __bf16* Ab = A + (size_t)bm * 128 * 1024;
  const __bf16* Bb = Bt + (size_t)bn * 128 * 1024;

  // staging: wave w covers rows [w*32, w*32+32), two 1KB wave-loads each for A,B
  const int srow = wid * 32 + (lane >> 2);  // +16 for second load
  const int scol = (lane & 3) * 8;
  __bf16* ldsA = &As[0][0] + wid * 1024;    // elements; +512 for second load
  __bf16* ldsB = &Bs[0][0] + wid * 1024;

  for (int k0 = 0; k0 < 1024; k0 += 32) {
    gload16(Ab + (size_t)srow * 1024 + k0 + scol, ldsA);
    gload16(Ab + (size_t)(srow + 16) * 1024 + k0 + scol, ldsA + 512);
    gload16(Bb + (size_t)srow * 1024 + k0 + scol, ldsB);
    gload16(Bb + (size_t)(srow + 16) * 1024 + k0 + scol, ldsB + 512);
    __syncthreads();  // vmcnt(0) drain inserted by compiler

    bf16x8 af[4], bfr[4];
#pragma unroll
    for (int mi = 0; mi < 4; ++mi)
      af[mi] = *(const bf16x8*)&As[wr * 64 + mi * 16 + lr][lg8];
#pragma unroll
    for (int ni = 0; ni < 4; ++ni)
      bfr[ni] = *(const bf16x8*)&Bs[wc * 64 + ni * 16 + lr][lg8];
#pragma unroll
    for (int mi = 0; mi < 4; ++mi)
#pragma unroll
      for (int ni = 0; ni < 4; ++ni)
        acc[mi][ni] = MFMA16(af[mi], bfr[ni], acc[mi][ni]);
    __syncthreads();  // protect LDS from next iteration's staging
  }

  // epilogue. C layout: row = (lane>>4)*4 + j, col = lane&15 (m89-verified)
  const int rb = bm * 128 + wr * 64 + lg * 4;
  const int cb = bn * 128 + wc * 64 + lr;
#pragma unroll
  for (int mi = 0; mi < 4; ++mi) {
#pragma unroll
    for (int ni = 0; ni < 4; ++ni) {
#pragma unroll
      for (int j = 0; j < 4; ++j) {
        float v = acc[mi][ni][j];
        int r = rb + mi * 16 + j;
        int c = cb + ni * 16;
        if constexpr (EPI == 0) {
          outf[(size_t)r * N + c] = v;
        } else {
          int which = c >> 10, within = c & 1023;
          int h = within >> 6, d = within & 63;
          int b = r >> 11, t = r & 2047;
          size_t idx = (((size_t)(b * TH + h)) * TT + t) * TD + d;
          if (which == 0)
            Qo[idx] = (__bf16)(v * 0.125f);  // fold 1/sqrt(64), exact in bf16
          else if (which == 1)
            Ko[idx] = (__bf16)v;
          else
            Vo[idx] = (__bf16)v;
        }
      }
    }
  }
}

// ---------------------------------------------------------------------------
// causal flash attention v6: BLOCK-COOPERATIVE K/V LDS staging (double-
// buffered, coalesced gload16 with pre-swizzled global source + XOR'd reads),
// 4 waves x 32 q-rows = 128-row block, chunk pairs (p, 15-p) -> exactly 36
// key-tiles per block. Swapped QK^T + static-max softmax (validated r3-r5).
// XCD swizzle groups all 8 blocks of one bh on one XCD (K/V set = 4MB = L2).
// Q [bh][t][d] (pre-scaled 1/8), K [bh][t][d], Vt [bh][d][t]; Y bf16 [b*T+t][C]
__global__ __launch_bounds__(256, 3) void k_attn(const __bf16* __restrict__ Qg,
                                                 const __bf16* __restrict__ Kg,
                                                 const __bf16* __restrict__ Vt,
                                                 __bf16* __restrict__ Y) {
  __shared__ __align__(16) __bf16 Ksh[2][64 * 64];     // [key][d], XOR-swizzled
  __shared__ __align__(16) __bf16 Vsh[2][64 * 64];     // [d][key], XOR-swizzled
  __shared__ __align__(16) __bf16 Plds[4][2][16][72];  // per-wave [f][q][key]
  // flat id: x (pair, 0..7) fastest, y = bh. XCD k gets bh in [8k, 8k+8).
  const int flat = blockIdx.x + (blockIdx.y << 3);
  const int W = (flat & 7) * 64 + (flat >> 3);
  const int bh = W >> 3, p = W & 7;
  const int tid = threadIdx.x, lane = tid & 63, w = tid >> 6;
  const int lr = lane & 15, lg = lane >> 4, lg8 = lg << 3, lg4 = lg << 2;

  const __bf16* Qb = Qg + ((size_t)bh * TT) * TD;
  const __bf16* Kb = Kg + ((size_t)bh * TT) * TD;
  const __bf16* Vb = Vt + ((size_t)bh * TD) * TT;
  const int b = bh >> 4, hh = bh & 15;
  __bf16* Yb = Y + ((size_t)b * TT) * TC + hh * TD;

  const int c0 = p, c1 = 15 - p;       // two 128-row q chunks
  const int nkt0 = 2 * c0 + 2;
  const int nt = nkt0 + 2 * c1 + 2;    // = 36 for every block

  constexpr float LOG2E = 1.44269504f;
  constexpr float CM = 12.0f * LOG2E;  // static max m0 = 12
  const f32x4 zero = {0.f, 0.f, 0.f, 0.f};

  // staging: 512 16B-chunks per tensor; thread covers slots tid, tid+256.
  // LDS slot (row, c16) holds global chunk (row, c16 ^ (row&7)) -> read with
  // the same XOR kills the stride-128B 16-way bank conflict (G4/m173).
  auto STAGE = [&](int bb, int kb) {
#pragma unroll
    for (int it = 0; it < 2; ++it) {
      int slot = tid + (it << 8);
      int r = slot >> 3;
      int sc = (slot & 7) ^ (r & 7);
      gload16(Kb + (size_t)(kb + r) * TD + sc * 8, &Ksh[bb][(it << 11) + (w << 9)]);
      gload16(Vb + (size_t)r * TT + kb + sc * 8, &Vsh[bb][(it << 11) + (w << 9)]);
    }
  };

  // per-chunk state
  int qw = c0 * 128 + w * 32;
  bf16x8 qf[2][2];
#pragma unroll
  for (int f = 0; f < 2; ++f)
#pragma unroll
    for (int h = 0; h < 2; ++h)
      qf[f][h] = *(const bf16x8*)(Qb + (size_t)(qw + f * 16 + lr) * TD + h * 32 + lg8);
  f32x4 o[2][4];
  f32x4 l4[2];
#pragma unroll
  for (int f = 0; f < 2; ++f) {
    l4[f] = zero;
#pragma unroll
    for (int df = 0; df < 4; ++df) o[f][df] = zero;
  }

  auto epilogue = [&]() {
#pragma unroll
    for (int f = 0; f < 2; ++f) {
      float L = (l4[f][0] + l4[f][1]) + (l4[f][2] + l4[f][3]);
      L += __shfl_xor(L, 16);
      L += __shfl_xor(L, 32);
      const float inv = 1.0f / L;  // for q = qw + f*16 + lr (uniform over lg)
#pragma unroll
      for (int j = 0; j < 4; ++j) {
        const float invr = __shfl(inv, lg4 + j);  // inv for row lg*4+j
        const int row = qw + f * 16 + lg4 + j;
#pragma unroll
        for (int df = 0; df < 4; ++df)
          Yb[(size_t)row * TC + df * 16 + lr] = (__bf16)(o[f][df][j] * invr);
      }
    }
  };

  int cur = 0;
  STAGE(0, 0);
  __syncthreads();  // compiler drains vmcnt before s_barrier

  for (int t = 0; t < nt; ++t) {
    // issue next tile's staging first (flies under this tile's compute)
    if (t + 1 < nt) {
      int t2 = t + 1;
      int kb2 = (t2 < nkt0 ? t2 : t2 - nkt0) << 6;
      STAGE(cur ^ 1, kb2);
    }
    // chunk transition: write chunk0 output, reset, load chunk1's Q
    if (t == nkt0) {
      epilogue();
      qw = c1 * 128 + w * 32;
#pragma unroll
      for (int f = 0; f < 2; ++f)
#pragma unroll
        for (int h = 0; h < 2; ++h)
          qf[f][h] = *(const bf16x8*)(Qb + (size_t)(qw + f * 16 + lr) * TD + h * 32 + lg8);
#pragma unroll
      for (int f = 0; f < 2; ++f) {
        l4[f] = zero;
#pragma unroll
        for (int df = 0; df < 4; ++df) o[f][df] = zero;
      }
    }

    const int kb = (t < nkt0 ? t : t - nkt0) << 6;
    const __bf16* Kt = Ksh[cur];
    const __bf16* Vst = Vsh[cur];

    // K as A-frag from LDS: row(key)=kf*16+lr, chunk col16 = (4h+lg)^(lr&7)
    bf16x8 kA[4][2];
#pragma unroll
    for (int kf = 0; kf < 4; ++kf)
#pragma unroll
      for (int h = 0; h < 2; ++h)
        kA[kf][h] = *(const bf16x8*)&Kt[(kf * 16 + lr) * 64 + (((h << 2) + lg) ^ (lr & 7)) * 8];

    // S^T = K Q^T: C[row=key=kf*16+lg*4+j][col=q=lr]
    f32x4 s4[2][4];
    __builtin_amdgcn_s_setprio(1);
#pragma unroll
    for (int f = 0; f < 2; ++f)
#pragma unroll
      for (int kf = 0; kf < 4; ++kf) {
        f32x4 z = zero;
        z = MFMA16(kA[kf][0], qf[f][0], z);
        z = MFMA16(kA[kf][1], qf[f][1], z);
        s4[f][kf] = z;
      }
    __builtin_amdgcn_s_setprio(0);

    // V as B-frag from LDS (read here; exp phase hides the lgkm latency)
    bf16x8 vB[4][2];
#pragma unroll
    for (int df = 0; df < 4; ++df)
#pragma unroll
      for (int h = 0; h < 2; ++h)
        vB[df][h] = *(const bf16x8*)&Vst[(df * 16 + lr) * 64 + (((h << 2) + lg) ^ (lr & 7)) * 8];

    // static-max exp: p = exp2(s*log2e - CM); mask by arg = -16384
#pragma unroll
    for (int f = 0; f < 2; ++f) {
      const int q = qw + f * 16 + lr;
      const bool diag = (kb + 63 > qw + f * 16);  // wave-uniform per f
#pragma unroll
      for (int kf = 0; kf < 4; ++kf) {
#pragma unroll
        for (int j = 0; j < 4; ++j) {
          float arg = __builtin_fmaf(s4[f][kf][j], LOG2E, -CM);
          if (diag) {
            int key = kb + kf * 16 + lg4 + j;
            if (key > q) arg = -16384.0f;
          }
          s4[f][kf][j] = exp2f(arg);
        }
        l4[f] += s4[f][kf];
        // P write: row=q(lr), cols kf*16+lg*4.. (4 consecutive keys -> b64)
        bf16x4 pk;
#pragma unroll
        for (int j = 0; j < 4; ++j) pk[j] = (__bf16)s4[f][kf][j];
        *(bf16x4*)&Plds[w][f][lr][kf * 16 + lg4] = pk;
      }
    }
    // (compiler inserts lgkmcnt wait for the Plds RAW dependency)

    // PV: P as A-frag (row=q=lr, k=key=lg*8+j +32h), V as B-frag
    __builtin_amdgcn_s_setprio(1);
#pragma unroll
    for (int f = 0; f < 2; ++f) {
      bf16x8 pa0 = *(const bf16x8*)&Plds[w][f][lr][lg8];
      bf16x8 pa1 = *(const bf16x8*)&Plds[w][f][lr][32 + lg8];
#pragma unroll
      for (int df = 0; df < 4; ++df) {
        o[f][df] = MFMA16(pa0, vB[df][0], o[f][df]);
        o[f][df] = MFMA16(pa1, vB[df][1], o[f][df]);
      }
    }
    __builtin_amdgcn_s_setprio(0);

    __syncthreads();  // staged buf ready for all; buf[cur] free to overwrite
    cur ^= 1;
  }

  epilogue();  // chunk1
}

// ---------------------------------------------------------------------------
extern "C" void kernel_launch(void* const* d_in, const int* in_sizes, int n_in,
                              void* d_out, int out_size, void* d_ws, size_t ws_size,
                              hipStream_t stream) {
  const float* x  = (const float*)d_in[0];
  const float* Wa = (const float*)d_in[1];
  const float* Wp = (const float*)d_in[2];
  float* out = (float*)d_out;

  char* ws = (char*)d_ws;
  size_t off = 0;
  auto alloc = [&](size_t bytes) { char* p = ws + off; off += bytes; return p; };
  __bf16* xb   = (__bf16*)alloc((size_t)TM * TC * 2);        // 16.8 MB (reused as Y)
  __bf16* wat  = (__bf16*)alloc((size_t)3 * TC * TC * 2);    //  6.3 MB
  __bf16* wpt  = (__bf16*)alloc((size_t)TC * TC * 2);        //  2.1 MB
  __bf16* Qb   = (__bf16*)alloc((size_t)TM * TC * 2);        // 16.8 MB
  __bf16* Kb   = (__bf16*)alloc((size_t)TM * TC * 2);        // 16.8 MB
  __bf16* Vb   = (__bf16*)alloc((size_t)TM * TC * 2);        // 16.8 MB
  __bf16* Vtb  = (__bf16*)alloc((size_t)TM * TC * 2);        // 16.8 MB
  __bf16* Yb   = xb;  // x_bf16 dead after GEMM1; alias as attention output

  // 1. x -> bf16
  k_convert<<<2048, 256, 0, stream>>>(x, xb, (TM * TC) / 4);
  // 2/3. W transposes -> [N][K] bf16
  k_transpose_w<<<dim3(48, 16), 256, 0, stream>>>(Wa, wat, 1024, 3072);
  k_transpose_w<<<dim3(16, 16), 256, 0, stream>>>(Wp, wpt, 1024, 1024);
  // 4. qkv = x @ W_attn, scatter to Q/K/V [B][H][T][D]
  k_gemm<1><<<dim3(24, 64), 256, 0, stream>>>(xb, wat, 3072, nullptr, Qb, Kb, Vb);
  // 5. V -> Vt [B][H][D][T]
  k_transpose_v<<<dim3(32, 64), 256, 0, stream>>>(Vb, Vtb);
  // 6. causal flash attention -> Y bf16 [B*T][C]
  k_attn<<<dim3(8, 64), 256, 0, stream>>>(Qb, Kb, Vtb, Yb);
  // 7. out = Y @ W_proj (f32 out)
  k_gemm<0><<<dim3(8, 64), 256, 0, stream>>>(Yb, wpt, 1024, out, nullptr, nullptr, nullptr);
}